// Round 6
// baseline (230.759 us; speedup 1.0000x reference)
//
#include <hip/hip_runtime.h>
#include <hip/hip_bf16.h>

// GraphSAGE 2-layer, N=50000, d=128->32->32, E=800000, fp32.
//
// R5 post-mortem: top profile rows are the harness's 268MB ws-poison fill
// (not ours). Remaining cost split (arithmetic): 2x k_agg random gathers
// (~35-50us each: 800k x 128B lines), sort ~28us, kproj ~17us, launches.
// R6: (1) neighbor-projection stored as bf16 (RNE) -> per-edge gather 64B
// instead of 128B (dominant traffic halves); self-projection stays fp32.
// (2) fuse L1-aggregation + L2-projection into k_aggproj (LDS h-tile),
// killing one kernel + 12.8MB h round-trip. (3) blkhist transposed so
// k_bscan streams int4 contiguously per thread.
//
// ws: zs1[N*32]f32 | zs2[N*32]f32 | zn1[N*32]bf16 | zn2[N*32]bf16 | ebuf[E]
//     | adj[E] | row_ptr[N+1] | bb[NB+1] | pad | blkhist[NB*GB]  (~26MB)

#define N_NODES 50000
#define NB 196   // coarse buckets = ceil(N/256)
#define GB 256   // blocks in bucket-count/scatter phases

__device__ __forceinline__ unsigned short f2bf(float f) {  // RNE
  unsigned int u = __float_as_uint(f);
  return (unsigned short)((u + 0x7fffu + ((u >> 16) & 1u)) >> 16);
}
__device__ __forceinline__ float bf2f(unsigned short v) {
  return __uint_as_float(((unsigned int)v) << 16);
}

// ---- projection: zn[n][0:32)=bf16(in@Wl), zs[n][0:32)=in@Wr --------------
// Block: 256 thr = 64 nodes x 64 cols, thread = 4 nodes x 4 cols.
__global__ __launch_bounds__(256) void kproj(
    const float* __restrict__ in, const float* __restrict__ Wl,
    const float* __restrict__ Wr, unsigned short* __restrict__ zn,
    float* __restrict__ zs, int N, int K) {
  __shared__ float xs[64 * 68];
  __shared__ float ws[64 * 64];
  const int t = threadIdx.x;
  const int n0 = blockIdx.x * 64;
  const int nvalid = (N - n0) < 64 ? (N - n0) : 64;
  const int tx = t & 15, ty = t >> 4;
  const int c0 = tx * 4, nl = ty * 4;

  float acc[4][4];
#pragma unroll
  for (int i = 0; i < 4; i++)
#pragma unroll
    for (int j = 0; j < 4; j++) acc[i][j] = 0.f;

  for (int kc = 0; kc < K; kc += 64) {
    const int KC = (K - kc) < 64 ? (K - kc) : 64;
    for (int i = t; i < KC * 32; i += 256) {
      int k = i >> 5, c = i & 31;
      ws[k * 64 + c] = Wl[(size_t)(kc + k) * 32 + c];
      ws[k * 64 + 32 + c] = Wr[(size_t)(kc + k) * 32 + c];
    }
    {
      const int kq = KC >> 2;
      const int sh = (KC == 64) ? 4 : 3;
      const int lim = nvalid * kq;
      for (int i = t; i < lim; i += 256) {
        int n = i >> sh, q = i & (kq - 1);
        float4 v = *(const float4*)(in + (size_t)(n0 + n) * K + kc + q * 4);
        *(float4*)(xs + n * 68 + q * 4) = v;
      }
    }
    __syncthreads();
    const float* x0 = xs + (nl + 0) * 68;
    const float* x1 = xs + (nl + 1) * 68;
    const float* x2 = xs + (nl + 2) * 68;
    const float* x3 = xs + (nl + 3) * 68;
    for (int k = 0; k < KC; k += 4) {
      float4 xa = *(const float4*)(x0 + k);
      float4 xb = *(const float4*)(x1 + k);
      float4 xc = *(const float4*)(x2 + k);
      float4 xd = *(const float4*)(x3 + k);
#pragma unroll
      for (int kk = 0; kk < 4; kk++) {
        float4 w = *(const float4*)(ws + (k + kk) * 64 + c0);
        float va = ((const float*)&xa)[kk];
        float vb = ((const float*)&xb)[kk];
        float vc = ((const float*)&xc)[kk];
        float vd = ((const float*)&xd)[kk];
        acc[0][0] += va * w.x; acc[0][1] += va * w.y;
        acc[0][2] += va * w.z; acc[0][3] += va * w.w;
        acc[1][0] += vb * w.x; acc[1][1] += vb * w.y;
        acc[1][2] += vb * w.z; acc[1][3] += vb * w.w;
        acc[2][0] += vc * w.x; acc[2][1] += vc * w.y;
        acc[2][2] += vc * w.z; acc[2][3] += vc * w.w;
        acc[3][0] += vd * w.x; acc[3][1] += vd * w.y;
        acc[3][2] += vd * w.z; acc[3][3] += vd * w.w;
      }
    }
    __syncthreads();
  }
#pragma unroll
  for (int i = 0; i < 4; i++) {
    int node = n0 + nl + i;
    if (node < N) {
      if (tx < 8) {
        ushort4 p;
        p.x = f2bf(acc[i][0]); p.y = f2bf(acc[i][1]);
        p.z = f2bf(acc[i][2]); p.w = f2bf(acc[i][3]);
        *(ushort4*)(zn + (size_t)node * 32 + c0) = p;
      } else {
        *(float4*)(zs + (size_t)node * 32 + (c0 - 32)) =
            make_float4(acc[i][0], acc[i][1], acc[i][2], acc[i][3]);
      }
    }
  }
}

// ---- phase A: per-block LDS histogram (transposed store) -----------------
__global__ __launch_bounds__(256) void k_bcount(const int* __restrict__ dst,
                                                int* __restrict__ blkhist,
                                                int E, int chunk) {
  __shared__ int h[NB];
  const int t = threadIdx.x, b = blockIdx.x;
  if (t < NB) h[t] = 0;
  __syncthreads();
  const int e0 = b * chunk;
  int e1 = e0 + chunk;
  if (e1 > E) e1 = E;
  for (int e = e0 + t; e < e1; e += 256) atomicAdd(&h[dst[e] >> 8], 1);
  __syncthreads();
  if (t < NB) blkhist[t * GB + b] = h[t];  // column-major: bucket-contiguous
}

// ---- phase B: per-bucket running sums (contiguous int4) + bases ----------
__global__ __launch_bounds__(256) void k_bscan(int* __restrict__ blkhist,
                                               int* __restrict__ bb, int E) {
  __shared__ int sc[256];
  const int t = threadIdx.x;
  int run = 0;
  if (t < NB) {
    int4* p = (int4*)(blkhist + t * GB);
    for (int q = 0; q < GB / 4; q++) {
      int4 v = p[q];
      int4 o;
      o.x = run; run += v.x;
      o.y = run; run += v.y;
      o.z = run; run += v.z;
      o.w = run; run += v.w;
      p[q] = o;
    }
  }
  sc[t] = (t < NB) ? run : 0;
  __syncthreads();
  for (int off = 1; off < 256; off <<= 1) {
    int tmp = (t >= off) ? sc[t - off] : 0;
    __syncthreads();
    sc[t] += tmp;
    __syncthreads();
  }
  if (t < NB) bb[t] = sc[t] - run;  // exclusive
  if (t == 0) bb[NB] = E;
}

// ---- phase C: scatter edges into coarse-bucket-grouped ebuf --------------
__global__ __launch_bounds__(256) void k_bscatter(
    const int* __restrict__ src, const int* __restrict__ dst,
    const int* __restrict__ blkhist, const int* __restrict__ bb,
    int* __restrict__ ebuf, int E, int chunk) {
  __shared__ int cur[NB];
  const int t = threadIdx.x, b = blockIdx.x;
  if (t < NB) cur[t] = bb[t] + blkhist[t * GB + b];
  __syncthreads();
  const int e0 = b * chunk;
  int e1 = e0 + chunk;
  if (e1 > E) e1 = E;
  for (int e = e0 + t; e < e1; e += 256) {
    int d = dst[e], s = src[e];
    int pos = atomicAdd(&cur[d >> 8], 1);
    ebuf[pos] = (s << 8) | (d & 255);
  }
}

// ---- phase D: per-bucket fine sort -> row_ptr + adj ----------------------
__global__ __launch_bounds__(256) void k_bsort(const int* __restrict__ ebuf,
                                               const int* __restrict__ bb,
                                               int* __restrict__ adj,
                                               int* __restrict__ row_ptr,
                                               int N, int E) {
  __shared__ int cnt[256];
  __shared__ int sc[256];
  const int t = threadIdx.x, k = blockIdx.x;
  const int r0 = bb[k], r1 = bb[k + 1];
  cnt[t] = 0;
  __syncthreads();
  for (int i = r0 + t; i < r1; i += 256) atomicAdd(&cnt[ebuf[i] & 255], 1);
  __syncthreads();
  sc[t] = cnt[t];
  __syncthreads();
  for (int off = 1; off < 256; off <<= 1) {
    int tmp = (t >= off) ? sc[t - off] : 0;
    __syncthreads();
    sc[t] += tmp;
    __syncthreads();
  }
  const int excl = sc[t] - cnt[t];
  const int node = (k << 8) + t;
  if (node < N) row_ptr[node] = r0 + excl;
  if (k == 0 && t == 0) row_ptr[N] = E;
  __syncthreads();
  cnt[t] = r0 + excl;  // cursor
  __syncthreads();
  for (int i = r0 + t; i < r1; i += 256) {
    int v = ebuf[i];
    int pos = atomicAdd(&cnt[v & 255], 1);
    adj[pos] = v >> 8;
  }
}

// ---- fused: L1 aggregation (bf16 gather -> relu h in LDS) + L2 GEMM ------
__global__ __launch_bounds__(256) void k_aggproj(
    const unsigned short* __restrict__ zn1, const float* __restrict__ zs1,
    const int* __restrict__ adj, const int* __restrict__ row_ptr,
    const float* __restrict__ b1, const float* __restrict__ W2l,
    const float* __restrict__ W2r, unsigned short* __restrict__ zn2,
    float* __restrict__ zs2, int N) {
  __shared__ float hs[64 * 36];
  __shared__ float ws2[32 * 64];
  const int t = threadIdx.x;
  const int n0 = blockIdx.x * 64;
  for (int i = t; i < 32 * 32; i += 256) {
    int k = i >> 5, c = i & 31;
    ws2[k * 64 + c] = W2l[k * 32 + c];
    ws2[k * 64 + 32 + c] = W2r[k * 32 + c];
  }
  const int j = t & 31, hw = t >> 5;  // 8 half-waves x 8 nodes each
  const float bj = b1[j];
  for (int p = 0; p < 8; p++) {
    int node = n0 + hw * 8 + p;
    float v = 0.f;
    if (node < N) {
      int r0 = row_ptr[node], r1 = row_ptr[node + 1];
      float a0 = 0.f, a1 = 0.f, a2 = 0.f, a3 = 0.f;
      int e = r0;
      for (; e + 4 <= r1; e += 4) {
        int s0 = adj[e], s1 = adj[e + 1], s2 = adj[e + 2], s3 = adj[e + 3];
        a0 += bf2f(zn1[(size_t)s0 * 32 + j]);
        a1 += bf2f(zn1[(size_t)s1 * 32 + j]);
        a2 += bf2f(zn1[(size_t)s2 * 32 + j]);
        a3 += bf2f(zn1[(size_t)s3 * 32 + j]);
      }
      for (; e < r1; ++e) a0 += bf2f(zn1[(size_t)adj[e] * 32 + j]);
      float sum = (a0 + a1) + (a2 + a3);
      int deg = r1 - r0;
      v = sum / (float)(deg > 1 ? deg : 1) + bj + zs1[(size_t)node * 32 + j];
      v = fmaxf(v, 0.f);
    }
    hs[(hw * 8 + p) * 36 + j] = v;
  }
  __syncthreads();
  const int tx = t & 15, ty = t >> 4;
  const int c0 = tx * 4, nl = ty * 4;
  float acc[4][4];
#pragma unroll
  for (int i = 0; i < 4; i++)
#pragma unroll
    for (int jj = 0; jj < 4; jj++) acc[i][jj] = 0.f;
  const float* x0 = hs + (nl + 0) * 36;
  const float* x1 = hs + (nl + 1) * 36;
  const float* x2 = hs + (nl + 2) * 36;
  const float* x3 = hs + (nl + 3) * 36;
  for (int k = 0; k < 32; k += 4) {
    float4 xa = *(const float4*)(x0 + k);
    float4 xb = *(const float4*)(x1 + k);
    float4 xc = *(const float4*)(x2 + k);
    float4 xd = *(const float4*)(x3 + k);
#pragma unroll
    for (int kk = 0; kk < 4; kk++) {
      float4 w = *(const float4*)(ws2 + (k + kk) * 64 + c0);
      float va = ((const float*)&xa)[kk];
      float vb = ((const float*)&xb)[kk];
      float vc = ((const float*)&xc)[kk];
      float vd = ((const float*)&xd)[kk];
      acc[0][0] += va * w.x; acc[0][1] += va * w.y;
      acc[0][2] += va * w.z; acc[0][3] += va * w.w;
      acc[1][0] += vb * w.x; acc[1][1] += vb * w.y;
      acc[1][2] += vb * w.z; acc[1][3] += vb * w.w;
      acc[2][0] += vc * w.x; acc[2][1] += vc * w.y;
      acc[2][2] += vc * w.z; acc[2][3] += vc * w.w;
      acc[3][0] += vd * w.x; acc[3][1] += vd * w.y;
      acc[3][2] += vd * w.z; acc[3][3] += vd * w.w;
    }
  }
#pragma unroll
  for (int i = 0; i < 4; i++) {
    int node = n0 + nl + i;
    if (node < N) {
      if (tx < 8) {
        ushort4 p;
        p.x = f2bf(acc[i][0]); p.y = f2bf(acc[i][1]);
        p.z = f2bf(acc[i][2]); p.w = f2bf(acc[i][3]);
        *(ushort4*)(zn2 + (size_t)node * 32 + c0) = p;
      } else {
        *(float4*)(zs2 + (size_t)node * 32 + (c0 - 32)) =
            make_float4(acc[i][0], acc[i][1], acc[i][2], acc[i][3]);
      }
    }
  }
}

// ---- final aggregation: out = mean_nbr(zn2) + b2 + zs2 -------------------
__global__ __launch_bounds__(256) void k_agg2(
    const unsigned short* __restrict__ zn, const float* __restrict__ zs,
    const int* __restrict__ adj, const int* __restrict__ row_ptr,
    const float* __restrict__ bias, float* __restrict__ out, int N) {
  const int t = threadIdx.x;
  const int j = t & 31;
  const int node = blockIdx.x * 8 + (t >> 5);
  if (node >= N) return;
  const int r0 = row_ptr[node], r1 = row_ptr[node + 1];
  float a0 = 0.f, a1 = 0.f, a2 = 0.f, a3 = 0.f;
  int e = r0;
  for (; e + 4 <= r1; e += 4) {
    int s0 = adj[e], s1 = adj[e + 1], s2 = adj[e + 2], s3 = adj[e + 3];
    a0 += bf2f(zn[(size_t)s0 * 32 + j]);
    a1 += bf2f(zn[(size_t)s1 * 32 + j]);
    a2 += bf2f(zn[(size_t)s2 * 32 + j]);
    a3 += bf2f(zn[(size_t)s3 * 32 + j]);
  }
  for (; e < r1; ++e) a0 += bf2f(zn[(size_t)adj[e] * 32 + j]);
  float sum = (a0 + a1) + (a2 + a3);
  const int deg = r1 - r0;
  float m = sum / (float)(deg > 1 ? deg : 1);
  out[(size_t)node * 32 + j] = m + bias[j] + zs[(size_t)node * 32 + j];
}

extern "C" void kernel_launch(void* const* d_in, const int* in_sizes, int n_in,
                              void* d_out, int out_size, void* d_ws,
                              size_t ws_size, hipStream_t stream) {
  const float* x = (const float*)d_in[0];
  const int* ei = (const int*)d_in[1];  // int32 (harness narrows int64)
  const float* W1l = (const float*)d_in[2];
  const float* b1 = (const float*)d_in[3];
  const float* W1r = (const float*)d_in[4];
  const float* W2l = (const float*)d_in[5];
  const float* b2 = (const float*)d_in[6];
  const float* W2r = (const float*)d_in[7];
  float* out = (float*)d_out;

  const int N = N_NODES;
  const int E = in_sizes[1] / 2;  // 800000

  float* zs1 = (float*)d_ws;                         // N*32 f32
  float* zs2 = zs1 + (size_t)N * 32;                 // N*32 f32
  unsigned short* zn1 = (unsigned short*)(zs2 + (size_t)N * 32);  // N*32 bf16
  unsigned short* zn2 = zn1 + (size_t)N * 32;        // N*32 bf16
  int* ebuf = (int*)(zn2 + (size_t)N * 32);          // E
  int* adj = ebuf + E;                               // E
  int* row_ptr = adj + E;                            // N+1
  int* bb = row_ptr + N + 1;                         // NB+1
  int* blkhist = (int*)(((size_t)(bb + NB + 1) + 15) & ~(size_t)15);  // NB*GB

  const int* srcp = ei;
  const int* dstp = ei + E;

  const int chunk = (E + GB - 1) / GB;
  const int nblk_proj = (N + 63) / 64;  // 782
  const int nblk_agg = (N + 7) / 8;     // 6250

  k_bcount<<<GB, 256, 0, stream>>>(dstp, blkhist, E, chunk);
  k_bscan<<<1, 256, 0, stream>>>(blkhist, bb, E);
  k_bscatter<<<GB, 256, 0, stream>>>(srcp, dstp, blkhist, bb, ebuf, E, chunk);
  k_bsort<<<NB, 256, 0, stream>>>(ebuf, bb, adj, row_ptr, N, E);

  kproj<<<nblk_proj, 256, 0, stream>>>(x, W1l, W1r, zn1, zs1, N, 128);
  k_aggproj<<<nblk_proj, 256, 0, stream>>>(zn1, zs1, adj, row_ptr, b1, W2l,
                                           W2r, zn2, zs2, N);
  k_agg2<<<nblk_agg, 256, 0, stream>>>(zn2, zs2, adj, row_ptr, b2, out, N);
}

// Round 8
// 192.180 us; speedup vs baseline: 1.2007x; 1.2007x over previous
//
#include <hip/hip_runtime.h>
#include <hip/hip_bf16.h>

// GraphSAGE 2-layer, N=50000, d=128->32->32, E=800000, fp32.
//
// R7 post-mortem: shfl-broadcast gather FAILED correctness (absmax 1.98 ~
// doubled mean -> suspect __shfl/__shfl_xor half-combine semantics under the
// interleaved pattern; coverage arithmetic re-verified by hand). R8: revert
// aggregation to the R5-PROVEN direct-walk (half-wave per node, scalar adj
// broadcast reads, no cross-lane ops), keeping the R6-proven bf16 zn gather
// (64B/edge instead of 128B) and 8-deep unroll for MLP. Every component is
// individually HW-proven now.
//
// ws: zs1[N*32]f32 | zs2[N*32]f32 | zn1[N*32]bf16 | zn2[N*32]bf16 | ebuf[E]
//     | adj[E] | row_ptr[N+1] | bb[NB+1] | pad | blkhist[NB*GB]
// d_out doubles as h[N][32] between k_agg(L1) and kproj(L2).

#define N_NODES 50000
#define NB 196   // coarse buckets = ceil(N/256)
#define GB 256   // blocks in bucket-count/scatter phases

__device__ __forceinline__ unsigned short f2bf(float f) {  // RNE
  unsigned int u = __float_as_uint(f);
  return (unsigned short)((u + 0x7fffu + ((u >> 16) & 1u)) >> 16);
}
__device__ __forceinline__ float bf2f(unsigned short v) {
  return __uint_as_float(((unsigned int)v) << 16);
}

// ---- projection: zn[n][0:32)=bf16(in@Wl), zs[n][0:32)=in@Wr --------------
// Block: 256 thr = 64 nodes x 64 cols, thread = 4 nodes x 4 cols.
__global__ __launch_bounds__(256) void kproj(
    const float* __restrict__ in, const float* __restrict__ Wl,
    const float* __restrict__ Wr, unsigned short* __restrict__ zn,
    float* __restrict__ zs, int N, int K) {
  __shared__ float xs[64 * 68];
  __shared__ float ws[64 * 64];
  const int t = threadIdx.x;
  const int n0 = blockIdx.x * 64;
  const int nvalid = (N - n0) < 64 ? (N - n0) : 64;
  const int tx = t & 15, ty = t >> 4;
  const int c0 = tx * 4, nl = ty * 4;

  float acc[4][4];
#pragma unroll
  for (int i = 0; i < 4; i++)
#pragma unroll
    for (int j = 0; j < 4; j++) acc[i][j] = 0.f;

  for (int kc = 0; kc < K; kc += 64) {
    const int KC = (K - kc) < 64 ? (K - kc) : 64;
    for (int i = t; i < KC * 32; i += 256) {
      int k = i >> 5, c = i & 31;
      ws[k * 64 + c] = Wl[(size_t)(kc + k) * 32 + c];
      ws[k * 64 + 32 + c] = Wr[(size_t)(kc + k) * 32 + c];
    }
    {
      const int kq = KC >> 2;
      const int sh = (KC == 64) ? 4 : 3;
      const int lim = nvalid * kq;
      for (int i = t; i < lim; i += 256) {
        int n = i >> sh, q = i & (kq - 1);
        float4 v = *(const float4*)(in + (size_t)(n0 + n) * K + kc + q * 4);
        *(float4*)(xs + n * 68 + q * 4) = v;
      }
    }
    __syncthreads();
    const float* x0 = xs + (nl + 0) * 68;
    const float* x1 = xs + (nl + 1) * 68;
    const float* x2 = xs + (nl + 2) * 68;
    const float* x3 = xs + (nl + 3) * 68;
    for (int k = 0; k < KC; k += 4) {
      float4 xa = *(const float4*)(x0 + k);
      float4 xb = *(const float4*)(x1 + k);
      float4 xc = *(const float4*)(x2 + k);
      float4 xd = *(const float4*)(x3 + k);
#pragma unroll
      for (int kk = 0; kk < 4; kk++) {
        float4 w = *(const float4*)(ws + (k + kk) * 64 + c0);
        float va = ((const float*)&xa)[kk];
        float vb = ((const float*)&xb)[kk];
        float vc = ((const float*)&xc)[kk];
        float vd = ((const float*)&xd)[kk];
        acc[0][0] += va * w.x; acc[0][1] += va * w.y;
        acc[0][2] += va * w.z; acc[0][3] += va * w.w;
        acc[1][0] += vb * w.x; acc[1][1] += vb * w.y;
        acc[1][2] += vb * w.z; acc[1][3] += vb * w.w;
        acc[2][0] += vc * w.x; acc[2][1] += vc * w.y;
        acc[2][2] += vc * w.z; acc[2][3] += vc * w.w;
        acc[3][0] += vd * w.x; acc[3][1] += vd * w.y;
        acc[3][2] += vd * w.z; acc[3][3] += vd * w.w;
      }
    }
    __syncthreads();
  }
#pragma unroll
  for (int i = 0; i < 4; i++) {
    int node = n0 + nl + i;
    if (node < N) {
      if (tx < 8) {
        ushort4 p;
        p.x = f2bf(acc[i][0]); p.y = f2bf(acc[i][1]);
        p.z = f2bf(acc[i][2]); p.w = f2bf(acc[i][3]);
        *(ushort4*)(zn + (size_t)node * 32 + c0) = p;
      } else {
        *(float4*)(zs + (size_t)node * 32 + (c0 - 32)) =
            make_float4(acc[i][0], acc[i][1], acc[i][2], acc[i][3]);
      }
    }
  }
}

// ---- phase A: per-block LDS histogram (transposed store) -----------------
__global__ __launch_bounds__(256) void k_bcount(const int* __restrict__ dst,
                                                int* __restrict__ blkhist,
                                                int E, int chunk) {
  __shared__ int h[NB];
  const int t = threadIdx.x, b = blockIdx.x;
  if (t < NB) h[t] = 0;
  __syncthreads();
  const int e0 = b * chunk;
  int e1 = e0 + chunk;
  if (e1 > E) e1 = E;
  for (int e = e0 + t; e < e1; e += 256) atomicAdd(&h[dst[e] >> 8], 1);
  __syncthreads();
  if (t < NB) blkhist[t * GB + b] = h[t];  // column-major: bucket-contiguous
}

// ---- phase B: per-bucket running sums (contiguous int4) + bases ----------
__global__ __launch_bounds__(256) void k_bscan(int* __restrict__ blkhist,
                                               int* __restrict__ bb, int E) {
  __shared__ int sc[256];
  const int t = threadIdx.x;
  int run = 0;
  if (t < NB) {
    int4* p = (int4*)(blkhist + t * GB);
    for (int q = 0; q < GB / 4; q++) {
      int4 v = p[q];
      int4 o;
      o.x = run; run += v.x;
      o.y = run; run += v.y;
      o.z = run; run += v.z;
      o.w = run; run += v.w;
      p[q] = o;
    }
  }
  sc[t] = (t < NB) ? run : 0;
  __syncthreads();
  for (int off = 1; off < 256; off <<= 1) {
    int tmp = (t >= off) ? sc[t - off] : 0;
    __syncthreads();
    sc[t] += tmp;
    __syncthreads();
  }
  if (t < NB) bb[t] = sc[t] - run;  // exclusive
  if (t == 0) bb[NB] = E;
}

// ---- phase C: scatter edges into coarse-bucket-grouped ebuf --------------
__global__ __launch_bounds__(256) void k_bscatter(
    const int* __restrict__ src, const int* __restrict__ dst,
    const int* __restrict__ blkhist, const int* __restrict__ bb,
    int* __restrict__ ebuf, int E, int chunk) {
  __shared__ int cur[NB];
  const int t = threadIdx.x, b = blockIdx.x;
  if (t < NB) cur[t] = bb[t] + blkhist[t * GB + b];
  __syncthreads();
  const int e0 = b * chunk;
  int e1 = e0 + chunk;
  if (e1 > E) e1 = E;
  for (int e = e0 + t; e < e1; e += 256) {
    int d = dst[e], s = src[e];
    int pos = atomicAdd(&cur[d >> 8], 1);
    ebuf[pos] = (s << 8) | (d & 255);
  }
}

// ---- phase D: per-bucket fine sort -> row_ptr + adj ----------------------
__global__ __launch_bounds__(256) void k_bsort(const int* __restrict__ ebuf,
                                               const int* __restrict__ bb,
                                               int* __restrict__ adj,
                                               int* __restrict__ row_ptr,
                                               int N, int E) {
  __shared__ int cnt[256];
  __shared__ int sc[256];
  const int t = threadIdx.x, k = blockIdx.x;
  const int r0 = bb[k], r1 = bb[k + 1];
  cnt[t] = 0;
  __syncthreads();
  for (int i = r0 + t; i < r1; i += 256) atomicAdd(&cnt[ebuf[i] & 255], 1);
  __syncthreads();
  sc[t] = cnt[t];
  __syncthreads();
  for (int off = 1; off < 256; off <<= 1) {
    int tmp = (t >= off) ? sc[t - off] : 0;
    __syncthreads();
    sc[t] += tmp;
    __syncthreads();
  }
  const int excl = sc[t] - cnt[t];
  const int node = (k << 8) + t;
  if (node < N) row_ptr[node] = r0 + excl;
  if (k == 0 && t == 0) row_ptr[N] = E;
  __syncthreads();
  cnt[t] = r0 + excl;  // cursor
  __syncthreads();
  for (int i = r0 + t; i < r1; i += 256) {
    int v = ebuf[i];
    int pos = atomicAdd(&cnt[v & 255], 1);
    adj[pos] = v >> 8;
  }
}

// ---- aggregation (R5-proven direct walk, bf16 gather, 8-deep unroll) -----
// Half-wave (32 lanes = 32 features) per node; no cross-lane ops.
__global__ __launch_bounds__(256) void k_agg(
    const unsigned short* __restrict__ zn, const float* __restrict__ zs,
    const int* __restrict__ adj, const int* __restrict__ row_ptr,
    const float* __restrict__ bias, float* __restrict__ out, int N,
    int do_relu) {
  const int t = threadIdx.x;
  const int j = t & 31;
  const int node = blockIdx.x * 8 + (t >> 5);
  if (node >= N) return;
  const int r0 = row_ptr[node], r1 = row_ptr[node + 1];
  float a0 = 0.f, a1 = 0.f, a2 = 0.f, a3 = 0.f;
  int e = r0;
  for (; e + 8 <= r1; e += 8) {
    int s0 = adj[e + 0], s1 = adj[e + 1], s2 = adj[e + 2], s3 = adj[e + 3];
    int s4 = adj[e + 4], s5 = adj[e + 5], s6 = adj[e + 6], s7 = adj[e + 7];
    float g0 = bf2f(zn[(size_t)s0 * 32 + j]);
    float g1 = bf2f(zn[(size_t)s1 * 32 + j]);
    float g2 = bf2f(zn[(size_t)s2 * 32 + j]);
    float g3 = bf2f(zn[(size_t)s3 * 32 + j]);
    float g4 = bf2f(zn[(size_t)s4 * 32 + j]);
    float g5 = bf2f(zn[(size_t)s5 * 32 + j]);
    float g6 = bf2f(zn[(size_t)s6 * 32 + j]);
    float g7 = bf2f(zn[(size_t)s7 * 32 + j]);
    a0 += g0 + g4;
    a1 += g1 + g5;
    a2 += g2 + g6;
    a3 += g3 + g7;
  }
  for (; e < r1; ++e) a0 += bf2f(zn[(size_t)adj[e] * 32 + j]);
  float sum = (a0 + a1) + (a2 + a3);
  const int deg = r1 - r0;
  float v = sum / (float)(deg > 1 ? deg : 1) + bias[j] +
            zs[(size_t)node * 32 + j];
  if (do_relu) v = fmaxf(v, 0.f);
  out[(size_t)node * 32 + j] = v;
}

extern "C" void kernel_launch(void* const* d_in, const int* in_sizes, int n_in,
                              void* d_out, int out_size, void* d_ws,
                              size_t ws_size, hipStream_t stream) {
  const float* x = (const float*)d_in[0];
  const int* ei = (const int*)d_in[1];  // int32 (harness narrows int64)
  const float* W1l = (const float*)d_in[2];
  const float* b1 = (const float*)d_in[3];
  const float* W1r = (const float*)d_in[4];
  const float* W2l = (const float*)d_in[5];
  const float* b2 = (const float*)d_in[6];
  const float* W2r = (const float*)d_in[7];
  float* out = (float*)d_out;

  const int N = N_NODES;
  const int E = in_sizes[1] / 2;  // 800000

  float* zs1 = (float*)d_ws;                         // N*32 f32
  float* zs2 = zs1 + (size_t)N * 32;                 // N*32 f32
  unsigned short* zn1 = (unsigned short*)(zs2 + (size_t)N * 32);  // N*32 bf16
  unsigned short* zn2 = zn1 + (size_t)N * 32;        // N*32 bf16
  int* ebuf = (int*)(zn2 + (size_t)N * 32);          // E
  int* adj = ebuf + E;                               // E
  int* row_ptr = adj + E;                            // N+1
  int* bb = row_ptr + N + 1;                         // NB+1
  int* blkhist = (int*)(((size_t)(bb + NB + 1) + 15) & ~(size_t)15);  // NB*GB

  const int* srcp = ei;
  const int* dstp = ei + E;

  const int chunk = (E + GB - 1) / GB;
  const int nblk_proj = (N + 63) / 64;  // 782
  const int nblk_agg = (N + 7) / 8;     // 6250

  k_bcount<<<GB, 256, 0, stream>>>(dstp, blkhist, E, chunk);
  k_bscan<<<1, 256, 0, stream>>>(blkhist, bb, E);
  k_bscatter<<<GB, 256, 0, stream>>>(srcp, dstp, blkhist, bb, ebuf, E, chunk);
  k_bsort<<<NB, 256, 0, stream>>>(ebuf, bb, adj, row_ptr, N, E);

  kproj<<<nblk_proj, 256, 0, stream>>>(x, W1l, W1r, zn1, zs1, N, 128);
  k_agg<<<nblk_agg, 256, 0, stream>>>(zn1, zs1, adj, row_ptr, b1, out, N, 1);
  kproj<<<nblk_proj, 256, 0, stream>>>(out, W2l, W2r, zn2, zs2, N, 32);
  k_agg<<<nblk_agg, 256, 0, stream>>>(zn2, zs2, adj, row_ptr, b2, out, N, 0);
}